// Round 3
// baseline (1208.300 us; speedup 1.0000x reference)
//
#include <hip/hip_runtime.h>

// EGA multi-headed attention, MI355X/gfx950. Split-bf16 (hi+lo) MFMA pipeline.
// Round 3: device-side mask dtype normalization (int32/bool/f32 -> uchar).
// Dims fixed: B=8, L=S=2048, E=1024, H=16, G=64, Ek=Ev=64, KD=VD=1024.

typedef float f32x4 __attribute__((ext_vector_type(4)));
typedef __bf16 bf16x8 __attribute__((ext_vector_type(8)));

#define DEV static __device__ __forceinline__

DEV unsigned short f2bf(float x){            // fp32 -> bf16 RNE
  unsigned u = __builtin_bit_cast(unsigned, x);
  u += 0x7fffu + ((u >> 16) & 1u);
  return (unsigned short)(u >> 16);
}
DEV float bf2f(unsigned short u){
  unsigned v = (unsigned)u << 16;
  return __builtin_bit_cast(float, v);
}
DEV float bflo(unsigned u){ return __builtin_bit_cast(float, u << 16); }
DEV float bfhi(unsigned u){ return __builtin_bit_cast(float, u & 0xffff0000u); }
DEV void split1(float x, unsigned short &h, unsigned short &l){
  h = f2bf(x);
  l = f2bf(x - bf2f(h));
}
DEV void split2pk(float a, float b, unsigned &h, unsigned &l){
  unsigned short ha, la, hb, lb;
  split1(a, ha, la); split1(b, hb, lb);
  h = (unsigned)ha | ((unsigned)hb << 16);
  l = (unsigned)la | ((unsigned)lb << 16);
}

// ---------------- mask dtype sniff + normalize to uchar ----------------
// Detect over the first n bytes viewed as n/4 uint32 words (in-bounds for all
// candidate dtypes): any word == 0x3F800000 -> float32; else any word > 1 ->
// byte-packed bool; else int32 (one word per element).
__global__ __launch_bounds__(256)
void mask_norm(const unsigned char* __restrict__ src, unsigned char* __restrict__ dst, int n)
{
  const unsigned* w = (const unsigned*)src;
  const int tid = threadIdx.x;
  int local = 0;
  for (int i = tid; i < n/4; i += 256){
    unsigned v = w[i];
    if (v == 0x3F800000u) local |= 2;
    else if (v > 1u)      local |= 1;
  }
  __shared__ int red[256];
  red[tid] = local;
  __syncthreads();
  for (int s = 128; s; s >>= 1){
    if (tid < s) red[tid] |= red[tid+s];
    __syncthreads();
  }
  const int r = red[0];
  const int mode = (r & 2) ? 2 : ((r & 1) ? 1 : 0);   // 2=f32, 1=u8, 0=i32
  for (int i = tid; i < n; i += 256){
    unsigned char v;
    if (mode == 1) v = src[i] ? 1 : 0;
    else           v = w[i]   ? 1 : 0;   // i32 / f32: one word per element
    dst[i] = v;
  }
}

// ---------------- 1024x1024 transpose, fp32 -> split bf16 planes ----------------
__global__ __launch_bounds__(256)
void transpose_split(const float* __restrict__ Wsrc,
                     unsigned short* __restrict__ Whi, unsigned short* __restrict__ Wlo,
                     int Kd, int Nd)
{
  __shared__ float t[64][65];
  const int tid = threadIdx.x;
  const int n0 = blockIdx.x * 64, k0 = blockIdx.y * 64;
  #pragma unroll
  for (int it = 0; it < 16; ++it){
    int e = it*256 + tid, r = e >> 6, c = e & 63;
    t[r][c] = Wsrc[(long)(k0+r)*Nd + (n0+c)];
  }
  __syncthreads();
  #pragma unroll
  for (int it = 0; it < 16; ++it){
    int e = it*256 + tid, r = e >> 6, c = e & 63;
    unsigned short h, l;
    split1(t[c][r], h, l);
    const long idx = (long)(n0+r)*Kd + (k0+c);
    Whi[idx] = h; Wlo[idx] = l;
  }
}

// ---------------- split-bf16 MFMA GEMM: C[m,n] = sum_k A[m,k]*Bt[n,k] ----------------
template<int TM, int AM, int BMODE, int CM, int EPI>
__global__ __launch_bounds__(256)
void gemm_sp(const void* __restrict__ Ap, const void* __restrict__ Ap2,
             const void* __restrict__ Bp, const void* __restrict__ Bp2,
             void* __restrict__ Cp, void* __restrict__ Cp2,
             const unsigned char* __restrict__ maskp,
             int K, int lda, int ldb, int ldc,
             long aB, long aH, long bB, long bH, long cB, long cH,
             int H2, int Ssz, float scale)
{
  constexpr int BN = 128, BK = 32, PAD = 8;
  constexpr int WM = TM/2, WN = BN/2;
  constexpr int FM = WM/16, FN = WN/16;
  __shared__ __align__(16) unsigned short AhS[TM][BK+PAD];
  __shared__ __align__(16) unsigned short AlS[TM][BK+PAD];
  __shared__ __align__(16) unsigned short BhS[BN][BK+PAD];
  __shared__ __align__(16) unsigned short BlS[BN][BK+PAD];

  const int tid = threadIdx.x;
  const int batch = blockIdx.z;
  const int b = batch / H2, h = batch - b*H2;
  const long aOff = (long)b*aB + (long)h*aH;
  const long bOff = (long)b*bB + (long)h*bH;
  const long cOff = (long)b*cB + (long)h*cH;
  const int nBase = blockIdx.x * BN;
  const int mBase = blockIdx.y * TM;
  const int wave = tid >> 6, lane = tid & 63;
  const int wm = wave >> 1, wn = wave & 1;
  const int srow = tid >> 2, scol = (tid & 3) * 8;

  f32x4 acc[FM][FN] = {};

  for (int k0 = 0; k0 < K; k0 += BK){
    if (k0) __syncthreads();
    #pragma unroll
    for (int c = 0; c < TM/64; ++c){
      const int row = c*64 + srow;
      const long g = aOff + (long)(mBase+row)*lda + (k0 + scol);
      if constexpr (AM == 0){
        const float* Af = (const float*)Ap;
        f32x4 f0 = *(const f32x4*)(Af + g);
        f32x4 f1 = *(const f32x4*)(Af + g + 4);
        uint4 uh, ul;
        split2pk(f0[0], f0[1], uh.x, ul.x);
        split2pk(f0[2], f0[3], uh.y, ul.y);
        split2pk(f1[0], f1[1], uh.z, ul.z);
        split2pk(f1[2], f1[3], uh.w, ul.w);
        *(uint4*)&AhS[row][scol] = uh;
        *(uint4*)&AlS[row][scol] = ul;
      } else {
        *(uint4*)&AhS[row][scol] = *(const uint4*)((const unsigned short*)Ap  + g);
        *(uint4*)&AlS[row][scol] = *(const uint4*)((const unsigned short*)Ap2 + g);
      }
    }
    #pragma unroll
    for (int c = 0; c < BN/64; ++c){
      const int row = c*64 + srow;
      const long g = bOff + (long)(nBase+row)*ldb + (k0 + scol);
      if constexpr (BMODE == 0){
        const float* Bf = (const float*)Bp;
        f32x4 f0 = *(const f32x4*)(Bf + g);
        f32x4 f1 = *(const f32x4*)(Bf + g + 4);
        uint4 uh, ul;
        split2pk(f0[0], f0[1], uh.x, ul.x);
        split2pk(f0[2], f0[3], uh.y, ul.y);
        split2pk(f1[0], f1[1], uh.z, ul.z);
        split2pk(f1[2], f1[3], uh.w, ul.w);
        *(uint4*)&BhS[row][scol] = uh;
        *(uint4*)&BlS[row][scol] = ul;
      } else {
        *(uint4*)&BhS[row][scol] = *(const uint4*)((const unsigned short*)Bp  + g);
        *(uint4*)&BlS[row][scol] = *(const uint4*)((const unsigned short*)Bp2 + g);
      }
    }
    __syncthreads();
    bf16x8 ah[FM], al[FM], bh[FN], bl[FN];
    #pragma unroll
    for (int mi = 0; mi < FM; ++mi){
      ah[mi] = *(const bf16x8*)&AhS[wm*WM + mi*16 + (lane & 15)][(lane >> 4) * 8];
      al[mi] = *(const bf16x8*)&AlS[wm*WM + mi*16 + (lane & 15)][(lane >> 4) * 8];
    }
    #pragma unroll
    for (int ni = 0; ni < FN; ++ni){
      bh[ni] = *(const bf16x8*)&BhS[wn*WN + ni*16 + (lane & 15)][(lane >> 4) * 8];
      bl[ni] = *(const bf16x8*)&BlS[wn*WN + ni*16 + (lane & 15)][(lane >> 4) * 8];
    }
    #pragma unroll
    for (int mi = 0; mi < FM; ++mi)
      #pragma unroll
      for (int ni = 0; ni < FN; ++ni){
        acc[mi][ni] = __builtin_amdgcn_mfma_f32_16x16x32_bf16(ah[mi], bh[ni], acc[mi][ni], 0, 0, 0);
        acc[mi][ni] = __builtin_amdgcn_mfma_f32_16x16x32_bf16(al[mi], bh[ni], acc[mi][ni], 0, 0, 0);
        acc[mi][ni] = __builtin_amdgcn_mfma_f32_16x16x32_bf16(ah[mi], bl[ni], acc[mi][ni], 0, 0, 0);
      }
  }

  const int cr = (lane >> 4) * 4, cc = lane & 15;
  #pragma unroll
  for (int mi = 0; mi < FM; ++mi)
    #pragma unroll
    for (int ni = 0; ni < FN; ++ni)
      #pragma unroll
      for (int r = 0; r < 4; ++r){
        const int row = mBase + wm*WM + mi*16 + cr + r;
        const int col = nBase + wn*WN + ni*16 + cc;
        float v = acc[mi][ni][r];
        if constexpr (EPI == 1){
          v *= scale;
          if (maskp[(long)b*Ssz + col]) v = -1e9f;
        }
        const long ci = cOff + (long)row*ldc + col;
        if constexpr (CM == 0){
          ((float*)Cp)[ci] = v;
        } else {
          unsigned short hh, ll;
          split1(v, hh, ll);
          ((unsigned short*)Cp)[ci]  = hh;
          ((unsigned short*)Cp2)[ci] = ll;
        }
      }
}

// ---------------- row softmax (width 2048), fp32 in-place ----------------
__global__ __launch_bounds__(256)
void softmax_inplace(float* __restrict__ data, int Wd)
{
  float* rp = data + (long)blockIdx.x * Wd;
  const int tid = threadIdx.x;
  const int lane = tid & 63, wv = tid >> 6;
  f32x4 v0 = ((const f32x4*)rp)[tid*2];
  f32x4 v1 = ((const f32x4*)rp)[tid*2+1];
  float m = fmaxf(fmaxf(fmaxf(v0[0],v0[1]),fmaxf(v0[2],v0[3])),
                  fmaxf(fmaxf(v1[0],v1[1]),fmaxf(v1[2],v1[3])));
  #pragma unroll
  for (int off = 32; off; off >>= 1) m = fmaxf(m, __shfl_xor(m, off));
  __shared__ float rm[4], rs[4];
  if (lane == 0) rm[wv] = m;
  __syncthreads();
  m = fmaxf(fmaxf(rm[0],rm[1]), fmaxf(rm[2],rm[3]));
  f32x4 e0, e1;
  #pragma unroll
  for (int i = 0; i < 4; ++i){ e0[i] = __expf(v0[i]-m); e1[i] = __expf(v1[i]-m); }
  float s = (e0[0]+e0[1]+e0[2]+e0[3]) + (e1[0]+e1[1]+e1[2]+e1[3]);
  #pragma unroll
  for (int off = 32; off; off >>= 1) s += __shfl_xor(s, off);
  if (lane == 0) rs[wv] = s;
  __syncthreads();
  s = (rs[0]+rs[1]) + (rs[2]+rs[3]);
  const float inv = 1.0f / s;
  ((f32x4*)rp)[tid*2]   = e0 * inv;
  ((f32x4*)rp)[tid*2+1] = e1 * inv;
}

// ---------------- batched 64xK @ Kx64 einsum, fp32 A x plane-pair B, split-K=4 ----------------
__global__ __launch_bounds__(256)
void einsum64(const float* __restrict__ A,
              const unsigned short* __restrict__ Bhip, const unsigned short* __restrict__ Blop,
              float* __restrict__ Cpart,
              int K, int lda, int ldb,
              long aB, long aH, long bB, long bH, int H2, int nbatch)
{
  __shared__ float As[64][68];
  __shared__ float Bs[64][68];
  const int tid = threadIdx.x;
  const int kc = blockIdx.x, batch = blockIdx.y;
  const int b = batch / H2, h = batch - b*H2;
  const float* Ab = A + (long)b*aB + (long)h*aH;
  const unsigned short* Bh = Bhip + (long)b*bB + (long)h*bH;
  const unsigned short* Bl = Blop + (long)b*bB + (long)h*bH;
  const int kchunk = K >> 2, kbeg = kc * kchunk;
  const int tm = tid >> 4, tn = tid & 15;
  const int sr = tid >> 4, sc = (tid & 15) * 4;
  float acc[4][4] = {};
  for (int ks = kbeg; ks < kbeg + kchunk; ks += 64){
    if (ks != kbeg) __syncthreads();
    #pragma unroll
    for (int p = 0; p < 4; ++p){
      const int g = p*16 + sr;
      f32x4 av = *(const f32x4*)&Ab[(long)g*lda + ks + sc];
      As[sc+0][g] = av[0]; As[sc+1][g] = av[1];
      As[sc+2][g] = av[2]; As[sc+3][g] = av[3];
      const int kr = p*16 + sr;
      ushort4 h4 = *(const ushort4*)&Bh[(long)(ks+kr)*ldb + sc];
      ushort4 l4 = *(const ushort4*)&Bl[(long)(ks+kr)*ldb + sc];
      Bs[kr][sc+0] = bf2f(h4.x) + bf2f(l4.x);
      Bs[kr][sc+1] = bf2f(h4.y) + bf2f(l4.y);
      Bs[kr][sc+2] = bf2f(h4.z) + bf2f(l4.z);
      Bs[kr][sc+3] = bf2f(h4.w) + bf2f(l4.w);
    }
    __syncthreads();
    #pragma unroll 8
    for (int k = 0; k < 64; ++k){
      f32x4 a4 = *(const f32x4*)&As[k][tm*4];
      f32x4 b4 = *(const f32x4*)&Bs[k][tn*4];
      #pragma unroll
      for (int i = 0; i < 4; ++i)
        #pragma unroll
        for (int j = 0; j < 4; ++j)
          acc[i][j] += a4[i] * b4[j];
    }
  }
  float* outp = Cpart + ((long)(kc*nbatch + batch) << 12);
  #pragma unroll
  for (int i = 0; i < 4; ++i){
    f32x4 v = { acc[i][0], acc[i][1], acc[i][2], acc[i][3] };
    *(f32x4*)&outp[(tm*4+i)*64 + tn*4] = v;
  }
}

// ---------------- sum split-K partials; write fp32 and/or split planes ----------------
__global__ __launch_bounds__(256)
void reduce64(const float* __restrict__ part, float* __restrict__ outf,
              unsigned short* __restrict__ outhi, unsigned short* __restrict__ outlo,
              int n4, int parts)
{
  const int idx = blockIdx.x*256 + threadIdx.x;
  if (idx >= n4) return;
  f32x4 s = ((const f32x4*)part)[idx];
  for (int p = 1; p < parts; ++p) s += ((const f32x4*)part)[(long)p*n4 + idx];
  if (outf) ((f32x4*)outf)[idx] = s;
  if (outhi){
    ushort4 uh, ul;
    split1(s[0], uh.x, ul.x); split1(s[1], uh.y, ul.y);
    split1(s[2], uh.z, ul.z); split1(s[3], uh.w, ul.w);
    ((ushort4*)outhi)[idx] = uh;
    ((ushort4*)outlo)[idx] = ul;
  }
}

// ---------------- stage 2: softmax(qs.gk^T*scale) -> l_attn + attn_out (fp32) ----------------
__global__ __launch_bounds__(256)
void stage2(const unsigned short* __restrict__ qhi, const unsigned short* __restrict__ qlo,
            const float* __restrict__ gk, const float* __restrict__ gv,
            float* __restrict__ lattn, float* __restrict__ aout, float scale)
{
  __shared__ f32x4 gkS[1024];
  __shared__ f32x4 gvS[1024];
  const int tid = threadIdx.x;
  const int bh = blockIdx.y;
  const int b = bh >> 4, h = bh & 15;
  const f32x4* gkp = (const f32x4*)(gk + (long)bh*4096);
  const f32x4* gvp = (const f32x4*)(gv + (long)bh*4096);
  #pragma unroll
  for (int i = 0; i < 4; ++i){
    gkS[i*256 + tid] = gkp[i*256 + tid];
    gvS[i*256 + tid] = gvp[i*256 + tid];
  }
  __syncthreads();
  const int l = blockIdx.x*256 + tid;

  const long qoff = ((long)b*2048 + l)*1024 + h*64;
  const unsigned short* qph = qhi + qoff;
  const unsigned short* qpl = qlo + qoff;
  f32x4 qf[16];
  #pragma unroll
  for (int i = 0; i < 8; ++i){
    uint4 uh = ((const uint4*)qph)[i];
    uint4 ul = ((const uint4*)qpl)[i];
    f32x4 t0 = { bflo(uh.x)+bflo(ul.x), bfhi(uh.x)+bfhi(ul.x),
                 bflo(uh.y)+bflo(ul.y), bfhi(uh.y)+bfhi(ul.y) };
    f32x4 t1 = { bflo(uh.z)+bflo(ul.z), bfhi(uh.z)+bfhi(ul.z),
                 bflo(uh.w)+bflo(ul.w), bfhi(uh.w)+bfhi(ul.w) };
    qf[2*i+0] = t0; qf[2*i+1] = t1;
  }
  float sm[64];
  float mx = -1e30f;
  #pragma unroll
  for (int g = 0; g < 64; ++g){
    f32x4 a = {0.f,0.f,0.f,0.f};
    #pragma unroll
    for (int d = 0; d < 16; ++d) a += qf[d] * gkS[g*16 + d];
    float s = ((a[0]+a[1]) + (a[2]+a[3])) * scale;
    sm[g] = s;
    mx = fmaxf(mx, s);
  }
  float sum = 0.f;
  #pragma unroll
  for (int g = 0; g < 64; ++g){ float p = __expf(sm[g]-mx); sm[g] = p; sum += p; }
  const float inv = 1.0f / sum;
  float* lp = lattn + ((long)bh*2048 + l)*64;
  #pragma unroll
  for (int g4 = 0; g4 < 16; ++g4){
    f32x4 pv = { sm[g4*4+0]*inv, sm[g4*4+1]*inv, sm[g4*4+2]*inv, sm[g4*4+3]*inv };
    ((f32x4*)lp)[g4] = pv;
  }
  f32x4 of[16];
  #pragma unroll
  for (int d = 0; d < 16; ++d){ f32x4 z = {0.f,0.f,0.f,0.f}; of[d] = z; }
  #pragma unroll
  for (int g = 0; g < 64; ++g){
    const float pg = sm[g]*inv;
    #pragma unroll
    for (int d = 0; d < 16; ++d) of[d] += pg * gvS[g*16 + d];
  }
  float* op = aout + qoff;
  #pragma unroll
  for (int i = 0; i < 16; ++i) ((f32x4*)op)[i] = of[i];
}

extern "C" void kernel_launch(void* const* d_in, const int* in_sizes, int n_in,
                              void* d_out, int out_size, void* d_ws, size_t ws_size,
                              hipStream_t stream)
{
  const float* query = (const float*)d_in[0];
  const float* key   = (const float*)d_in[1];
  const float* value = (const float*)d_in[2];
  const unsigned char* mask_raw = (const unsigned char*)d_in[4];  // dtype sniffed on device
  const float* Wq = (const float*)d_in[6];
  const float* Wk = (const float*)d_in[7];
  const float* Wv = (const float*)d_in[8];
  const float* Wi = (const float*)d_in[9];
  const float* Wo = (const float*)d_in[10];
  float* out0 = (float*)d_out;                  // (B,L,E)   = 16,777,216 f32
  float* out1 = out0 + 16777216;                // (B,H,L,G) = 16,777,216 f32

  // ---- workspace layout (~276 MiB) ----
  unsigned short* WoT_hi = (unsigned short*)d_ws;
  unsigned short* WoT_lo = WoT_hi + 1048576;
  unsigned short* WqT_hi = WoT_lo + 1048576;
  unsigned short* WqT_lo = WqT_hi + 1048576;
  unsigned short* WkT_hi = WqT_lo + 1048576;
  unsigned short* WkT_lo = WkT_hi + 1048576;
  unsigned short* WvT_hi = WkT_lo + 1048576;
  unsigned short* WvT_lo = WvT_hi + 1048576;
  unsigned short* WiT_hi = WvT_lo + 1048576;
  unsigned short* WiT_lo = WiT_hi + 1048576;
  unsigned short* qs_hi  = WiT_lo + 1048576;
  unsigned short* qs_lo  = qs_hi + 16777216;
  unsigned short* kk_hi  = qs_lo + 16777216;
  unsigned short* kk_lo  = kk_hi + 16777216;
  unsigned short* vs_hi  = kk_lo + 16777216;
  unsigned short* vs_lo  = vs_hi + 16777216;
  float* scoref = (float*)(vs_lo + 16777216);
  // overlay on Wq..Wi planes (dead after the ips GEMM):
  float* part = (float*)WqT_hi;                           // 8 MiB (WqT+WkT planes)
  unsigned short* gqs_hi = (unsigned short*)(part + 2097152);  // WvT_hi 1st half
  unsigned short* gqs_lo = gqs_hi + 524288;                    // WvT_hi 2nd half
  float* gk_f = (float*)(gqs_lo + 524288);                     // WvT_lo
  float* gv_f = gk_f + 524288;                                 // WiT_hi
  unsigned char* mask_ws = (unsigned char*)(gv_f + 524288);    // WiT_lo head (16 KiB)
  float* attn_out = (float*)kk_hi;                             // dead after gk einsum

  const dim3 blk(256);
  const float scale = 0.125f;   // 1/sqrt(64)

  // 1) weight transposes -> split planes
  transpose_split<<<dim3(16,16), blk, 0, stream>>>(Wq, WqT_hi, WqT_lo, 1024, 1024);
  transpose_split<<<dim3(16,16), blk, 0, stream>>>(Wk, WkT_hi, WkT_lo, 1024, 1024);
  transpose_split<<<dim3(16,16), blk, 0, stream>>>(Wv, WvT_hi, WvT_lo, 1024, 1024);
  transpose_split<<<dim3(16,16), blk, 0, stream>>>(Wi, WiT_hi, WiT_lo, 1024, 1024);
  transpose_split<<<dim3(16,16), blk, 0, stream>>>(Wo, WoT_hi, WoT_lo, 1024, 1024);

  // 2) projections (16384x1024)@(1024x1024) -> split planes
  gemm_sp<128,0,1,1,0><<<dim3(8,128,1), blk, 0, stream>>>(
      query, nullptr, WqT_hi, WqT_lo, qs_hi, qs_lo, nullptr,
      1024, 1024,1024,1024, 0,0, 0,0, 0,0, 1, 2048, 1.f);
  gemm_sp<128,0,1,1,0><<<dim3(8,128,1), blk, 0, stream>>>(
      key,   nullptr, WkT_hi, WkT_lo, kk_hi, kk_lo, nullptr,
      1024, 1024,1024,1024, 0,0, 0,0, 0,0, 1, 2048, 1.f);
  gemm_sp<128,0,1,1,0><<<dim3(8,128,1), blk, 0, stream>>>(
      value, nullptr, WvT_hi, WvT_lo, vs_hi, vs_lo, nullptr,
      1024, 1024,1024,1024, 0,0, 0,0, 0,0, 1, 2048, 1.f);

  // 3) ipsT[b][hg][l] = WiT @ q[b]^T -> fp32; softmax over L in place
  gemm_sp<128,1,0,0,0><<<dim3(16,8,8), blk, 0, stream>>>(
      WiT_hi, WiT_lo, query, nullptr, scoref, nullptr, nullptr,
      1024, 1024,1024,2048, 0,0, 2097152L,0, 2097152L,0, 1, 2048, 1.f);
  // WiT planes now dead -> normalize mask into the WiT_lo overlay
  mask_norm<<<1, blk, 0, stream>>>(mask_raw, mask_ws, 16384);
  softmax_inplace<<<8192, blk, 0, stream>>>(scoref, 2048);

  // 4) gqs[bh] = wts[bh](64xL) @ qs[bh](Lx64) -> split planes
  einsum64<<<dim3(4,128), blk, 0, stream>>>(scoref, qs_hi, qs_lo, part,
      2048, 2048, 1024, 2097152L, 131072L, 2097152L, 64L, 16, 128);
  reduce64<<<512, blk, 0, stream>>>(part, nullptr, gqs_hi, gqs_lo, 131072, 4);

  // 5) g_scores[bh] = gqs@kk^T * scale, mask -> fp32; softmax in place -> g_attn
  gemm_sp<64,1,1,0,1><<<dim3(16,1,128), blk, 0, stream>>>(
      gqs_hi, gqs_lo, kk_hi, kk_lo, scoref, nullptr, mask_ws,
      64, 64,1024,2048, 65536L,4096L, 2097152L,64L, 2097152L,131072L, 16, 2048, scale);
  softmax_inplace<<<8192, blk, 0, stream>>>(scoref, 2048);

  // 6) gk/gv[bh] = g_attn[bh](64xS) @ {kk,vs}[bh](Sx64) -> fp32
  einsum64<<<dim3(4,128), blk, 0, stream>>>(scoref, kk_hi, kk_lo, part,
      2048, 2048, 1024, 2097152L, 131072L, 2097152L, 64L, 16, 128);
  reduce64<<<512, blk, 0, stream>>>(part, gk_f, nullptr, nullptr, 131072, 4);
  einsum64<<<dim3(4,128), blk, 0, stream>>>(scoref, vs_hi, vs_lo, part,
      2048, 2048, 1024, 2097152L, 131072L, 2097152L, 64L, 16, 128);
  reduce64<<<512, blk, 0, stream>>>(part, gv_f, nullptr, nullptr, 131072, 4);

  // 7) stage 2: l_attn (out1) + attn_out fp32 (over dead kk planes)
  stage2<<<dim3(8,128), blk, 0, stream>>>(qs_hi, qs_lo, gk_f, gv_f, out1, attn_out, scale);

  // 8) out0 = attn_out @ Wo
  gemm_sp<128,0,1,0,0><<<dim3(8,128,1), blk, 0, stream>>>(
      attn_out, nullptr, WoT_hi, WoT_lo, out0, nullptr, nullptr,
      1024, 1024,1024,1024, 0,0, 0,0, 0,0, 1, 2048, 1.f);

  (void)in_sizes; (void)n_in; (void)out_size; (void)ws_size;
}

// Round 4
// 1008.812 us; speedup vs baseline: 1.1977x; 1.1977x over previous
//
#include <hip/hip_runtime.h>

// EGA multi-headed attention, MI355X/gfx950.
// Round 4: f16 asymmetric 2-term MFMA GEMMs (A=hi+lo, B=hi; err ~2^-11),
//          stage2 rewritten as 2-pass online softmax (no reg-array spill),
//          fused gk/gv dual einsum.
// Dims fixed: B=8, L=S=2048, E=1024, H=16, G=64, Ek=Ev=64, KD=VD=1024.

typedef float f32x4 __attribute__((ext_vector_type(4)));
typedef _Float16 f16x8 __attribute__((ext_vector_type(8)));

#define DEV static __device__ __forceinline__

DEV unsigned short f2h(float x){
  _Float16 h = (_Float16)x;
  return __builtin_bit_cast(unsigned short, h);
}
DEV float h2f(unsigned short u){
  return (float)__builtin_bit_cast(_Float16, u);
}
DEV void split1h(float x, unsigned short &h, unsigned short &l){
  h = f2h(x);
  l = f2h(x - h2f(h));     // residual exact in f32; second rounding ~2^-22
}
DEV unsigned pk2h(float a, float b){
  return (unsigned)f2h(a) | ((unsigned)f2h(b) << 16);
}
DEV void split2pkh(float a, float b, unsigned &h, unsigned &l){
  unsigned short ha, la, hb, lb;
  split1h(a, ha, la); split1h(b, hb, lb);
  h = (unsigned)ha | ((unsigned)hb << 16);
  l = (unsigned)la | ((unsigned)lb << 16);
}

// ---------------- mask dtype sniff + normalize to uchar ----------------
__global__ __launch_bounds__(256)
void mask_norm(const unsigned char* __restrict__ src, unsigned char* __restrict__ dst, int n)
{
  const unsigned* w = (const unsigned*)src;
  const int tid = threadIdx.x;
  int local = 0;
  for (int i = tid; i < n/4; i += 256){
    unsigned v = w[i];
    if (v == 0x3F800000u) local |= 2;
    else if (v > 1u)      local |= 1;
  }
  __shared__ int red[256];
  red[tid] = local;
  __syncthreads();
  for (int s = 128; s; s >>= 1){
    if (tid < s) red[tid] |= red[tid+s];
    __syncthreads();
  }
  const int r = red[0];
  const int mode = (r & 2) ? 2 : ((r & 1) ? 1 : 0);   // 2=f32, 1=u8, 0=i32
  for (int i = tid; i < n; i += 256){
    unsigned char v;
    if (mode == 1) v = src[i] ? 1 : 0;
    else           v = w[i]   ? 1 : 0;
    dst[i] = v;
  }
}

// ---------------- 1024x1024 transpose, fp32 -> split f16 planes ----------------
__global__ __launch_bounds__(256)
void transpose_split(const float* __restrict__ Wsrc,
                     unsigned short* __restrict__ Whi, unsigned short* __restrict__ Wlo,
                     int Kd, int Nd)
{
  __shared__ float t[64][65];
  const int tid = threadIdx.x;
  const int n0 = blockIdx.x * 64, k0 = blockIdx.y * 64;
  #pragma unroll
  for (int it = 0; it < 16; ++it){
    int e = it*256 + tid, r = e >> 6, c = e & 63;
    t[r][c] = Wsrc[(long)(k0+r)*Nd + (n0+c)];
  }
  __syncthreads();
  #pragma unroll
  for (int it = 0; it < 16; ++it){
    int e = it*256 + tid, r = e >> 6, c = e & 63;
    unsigned short h, l;
    split1h(t[c][r], h, l);
    const long idx = (long)(n0+r)*Kd + (k0+c);
    Whi[idx] = h; Wlo[idx] = l;
  }
}

// ---------------- f16 2-term MFMA GEMM: C[m,n] = sum_k A[m,k]*Bt[n,k] ----------------
// A: 2 planes (AM=0: fp32 split-on-stage; AM=1: pre-split planes Ap/Ap2).
// B: 1 plane  (BMODE=0: fp32 cvt-on-stage;  BMODE=1: pre-split hi plane).
// CM: 0 = fp32 out; 1 = split f16 planes out.  EPI==1: scale+mask epilogue.
template<int TM, int AM, int BMODE, int CM, int EPI>
__global__ __launch_bounds__(256)
void gemm_sp(const void* __restrict__ Ap, const void* __restrict__ Ap2,
             const void* __restrict__ Bp,
             void* __restrict__ Cp, void* __restrict__ Cp2,
             const unsigned char* __restrict__ maskp,
             int K, int lda, int ldb, int ldc,
             long aB, long aH, long bB, long bH, long cB, long cH,
             int H2, int Ssz, float scale)
{
  constexpr int BN = 128, BK = 32, PAD = 8;
  constexpr int WM = TM/2, WN = BN/2;
  constexpr int FM = WM/16, FN = WN/16;
  __shared__ __align__(16) unsigned short AhS[TM][BK+PAD];
  __shared__ __align__(16) unsigned short AlS[TM][BK+PAD];
  __shared__ __align__(16) unsigned short BhS[BN][BK+PAD];

  const int tid = threadIdx.x;
  const int batch = blockIdx.z;
  const int b = batch / H2, h = batch - b*H2;
  const long aOff = (long)b*aB + (long)h*aH;
  const long bOff = (long)b*bB + (long)h*bH;
  const long cOff = (long)b*cB + (long)h*cH;
  const int nBase = blockIdx.x * BN;
  const int mBase = blockIdx.y * TM;
  const int wave = tid >> 6, lane = tid & 63;
  const int wm = wave >> 1, wn = wave & 1;
  const int srow = tid >> 2, scol = (tid & 3) * 8;

  f32x4 acc[FM][FN] = {};

  for (int k0 = 0; k0 < K; k0 += BK){
    if (k0) __syncthreads();
    #pragma unroll
    for (int c = 0; c < TM/64; ++c){
      const int row = c*64 + srow;
      const long g = aOff + (long)(mBase+row)*lda + (k0 + scol);
      if constexpr (AM == 0){
        const float* Af = (const float*)Ap;
        f32x4 f0 = *(const f32x4*)(Af + g);
        f32x4 f1 = *(const f32x4*)(Af + g + 4);
        uint4 uh, ul;
        split2pkh(f0[0], f0[1], uh.x, ul.x);
        split2pkh(f0[2], f0[3], uh.y, ul.y);
        split2pkh(f1[0], f1[1], uh.z, ul.z);
        split2pkh(f1[2], f1[3], uh.w, ul.w);
        *(uint4*)&AhS[row][scol] = uh;
        *(uint4*)&AlS[row][scol] = ul;
      } else {
        *(uint4*)&AhS[row][scol] = *(const uint4*)((const unsigned short*)Ap  + g);
        *(uint4*)&AlS[row][scol] = *(const uint4*)((const unsigned short*)Ap2 + g);
      }
    }
    #pragma unroll
    for (int c = 0; c < BN/64; ++c){
      const int row = c*64 + srow;
      const long g = bOff + (long)(nBase+row)*ldb + (k0 + scol);
      if constexpr (BMODE == 0){
        const float* Bf = (const float*)Bp;
        f32x4 f0 = *(const f32x4*)(Bf + g);
        f32x4 f1 = *(const f32x4*)(Bf + g + 4);
        uint4 u;
        u.x = pk2h(f0[0], f0[1]); u.y = pk2h(f0[2], f0[3]);
        u.z = pk2h(f1[0], f1[1]); u.w = pk2h(f1[2], f1[3]);
        *(uint4*)&BhS[row][scol] = u;
      } else {
        *(uint4*)&BhS[row][scol] = *(const uint4*)((const unsigned short*)Bp + g);
      }
    }
    __syncthreads();
    f16x8 ah[FM], al[FM], bh[FN];
    #pragma unroll
    for (int mi = 0; mi < FM; ++mi){
      ah[mi] = *(const f16x8*)&AhS[wm*WM + mi*16 + (lane & 15)][(lane >> 4) * 8];
      al[mi] = *(const f16x8*)&AlS[wm*WM + mi*16 + (lane & 15)][(lane >> 4) * 8];
    }
    #pragma unroll
    for (int ni = 0; ni < FN; ++ni)
      bh[ni] = *(const f16x8*)&BhS[wn*WN + ni*16 + (lane & 15)][(lane >> 4) * 8];
    #pragma unroll
    for (int mi = 0; mi < FM; ++mi)
      #pragma unroll
      for (int ni = 0; ni < FN; ++ni){
        acc[mi][ni] = __builtin_amdgcn_mfma_f32_16x16x32_f16(ah[mi], bh[ni], acc[mi][ni], 0, 0, 0);
        acc[mi][ni] = __builtin_amdgcn_mfma_f32_16x16x32_f16(al[mi], bh[ni], acc[mi][ni], 0, 0, 0);
      }
  }

  const int cr = (lane >> 4) * 4, cc = lane & 15;
  #pragma unroll
  for (int mi = 0; mi < FM; ++mi)
    #pragma unroll
    for (int ni = 0; ni < FN; ++ni)
      #pragma unroll
      for (int r = 0; r < 4; ++r){
        const int row = mBase + wm*WM + mi*16 + cr + r;
        const int col = nBase + wn*WN + ni*16 + cc;
        float v = acc[mi][ni][r];
        if constexpr (EPI == 1){
          v *= scale;
          if (maskp[(long)b*Ssz + col]) v = -1e9f;
        }
        const long ci = cOff + (long)row*ldc + col;
        if constexpr (CM == 0){
          ((float*)Cp)[ci] = v;
        } else {
          unsigned short hh, ll;
          split1h(v, hh, ll);
          ((unsigned short*)Cp)[ci]  = hh;
          ((unsigned short*)Cp2)[ci] = ll;
        }
      }
}

// ---------------- row softmax (width 2048), fp32 in-place ----------------
__global__ __launch_bounds__(256)
void softmax_inplace(float* __restrict__ data, int Wd)
{
  float* rp = data + (long)blockIdx.x * Wd;
  const int tid = threadIdx.x;
  const int lane = tid & 63, wv = tid >> 6;
  f32x4 v0 = ((const f32x4*)rp)[tid*2];
  f32x4 v1 = ((const f32x4*)rp)[tid*2+1];
  float m = fmaxf(fmaxf(fmaxf(v0[0],v0[1]),fmaxf(v0[2],v0[3])),
                  fmaxf(fmaxf(v1[0],v1[1]),fmaxf(v1[2],v1[3])));
  #pragma unroll
  for (int off = 32; off; off >>= 1) m = fmaxf(m, __shfl_xor(m, off));
  __shared__ float rm[4], rs[4];
  if (lane == 0) rm[wv] = m;
  __syncthreads();
  m = fmaxf(fmaxf(rm[0],rm[1]), fmaxf(rm[2],rm[3]));
  f32x4 e0, e1;
  #pragma unroll
  for (int i = 0; i < 4; ++i){ e0[i] = __expf(v0[i]-m); e1[i] = __expf(v1[i]-m); }
  float s = (e0[0]+e0[1]+e0[2]+e0[3]) + (e1[0]+e1[1]+e1[2]+e1[3]);
  #pragma unroll
  for (int off = 32; off; off >>= 1) s += __shfl_xor(s, off);
  if (lane == 0) rs[wv] = s;
  __syncthreads();
  s = (rs[0]+rs[1]) + (rs[2]+rs[3]);
  const float inv = 1.0f / s;
  ((f32x4*)rp)[tid*2]   = e0 * inv;
  ((f32x4*)rp)[tid*2+1] = e1 * inv;
}

// ---------------- batched 64xK @ Kx64 einsum, fp32 A x f16 plane-pair B, split-K ----------------
__global__ __launch_bounds__(256)
void einsum64(const float* __restrict__ A,
              const unsigned short* __restrict__ Bhip, const unsigned short* __restrict__ Blop,
              float* __restrict__ Cpart,
              int K, int KC, int lda, int ldb,
              long aB, long aH, long bB, long bH, int H2, int nbatch)
{
  __shared__ float As[64][68];
  __shared__ float Bs[64][68];
  const int tid = threadIdx.x;
  const int kc = blockIdx.x, batch = blockIdx.y;
  const int b = batch / H2, h = batch - b*H2;
  const float* Ab = A + (long)b*aB + (long)h*aH;
  const unsigned short* Bh = Bhip + (long)b*bB + (long)h*bH;
  const unsigned short* Bl = Blop + (long)b*bB + (long)h*bH;
  const int kchunk = K / KC, kbeg = kc * kchunk;
  const int tm = tid >> 4, tn = tid & 15;
  const int sr = tid >> 4, sc = (tid & 15) * 4;
  float acc[4][4] = {};
  for (int ks = kbeg; ks < kbeg + kchunk; ks += 64){
    if (ks != kbeg) __syncthreads();
    #pragma unroll
    for (int p = 0; p < 4; ++p){
      const int g = p*16 + sr;
      f32x4 av = *(const f32x4*)&Ab[(long)g*lda + ks + sc];
      As[sc+0][g] = av[0]; As[sc+1][g] = av[1];
      As[sc+2][g] = av[2]; As[sc+3][g] = av[3];
      const int kr = p*16 + sr;
      ushort4 h4 = *(const ushort4*)&Bh[(long)(ks+kr)*ldb + sc];
      ushort4 l4 = *(const ushort4*)&Bl[(long)(ks+kr)*ldb + sc];
      Bs[kr][sc+0] = h2f(h4.x) + h2f(l4.x);
      Bs[kr][sc+1] = h2f(h4.y) + h2f(l4.y);
      Bs[kr][sc+2] = h2f(h4.z) + h2f(l4.z);
      Bs[kr][sc+3] = h2f(h4.w) + h2f(l4.w);
    }
    __syncthreads();
    #pragma unroll 8
    for (int k = 0; k < 64; ++k){
      f32x4 a4 = *(const f32x4*)&As[k][tm*4];
      f32x4 b4 = *(const f32x4*)&Bs[k][tn*4];
      #pragma unroll
      for (int i = 0; i < 4; ++i)
        #pragma unroll
        for (int j = 0; j < 4; ++j)
          acc[i][j] += a4[i] * b4[j];
    }
  }
  float* outp = Cpart + ((long)(kc*nbatch + batch) << 12);
  #pragma unroll
  for (int i = 0; i < 4; ++i){
    f32x4 v = { acc[i][0], acc[i][1], acc[i][2], acc[i][3] };
    *(f32x4*)&outp[(tm*4+i)*64 + tn*4] = v;
  }
}

// ---------------- dual einsum: shared A, two B plane-pairs (kk & vs) ----------------
__global__ __launch_bounds__(256)
void einsum64_dual(const float* __restrict__ A,
                   const unsigned short* __restrict__ B1h, const unsigned short* __restrict__ B1l,
                   const unsigned short* __restrict__ B2h, const unsigned short* __restrict__ B2l,
                   float* __restrict__ P1, float* __restrict__ P2,
                   int K, int KC, int lda, int ldb,
                   long aB, long aH, long bB, long bH, int H2, int nbatch)
{
  __shared__ float As[64][68];
  __shared__ float B1s[64][68];
  __shared__ float B2s[64][68];
  const int tid = threadIdx.x;
  const int kc = blockIdx.x, batch = blockIdx.y;
  const int b = batch / H2, h = batch - b*H2;
  const float* Ab = A + (long)b*aB + (long)h*aH;
  const unsigned short* b1h = B1h + (long)b*bB + (long)h*bH;
  const unsigned short* b1l = B1l + (long)b*bB + (long)h*bH;
  const unsigned short* b2h = B2h + (long)b*bB + (long)h*bH;
  const unsigned short* b2l = B2l + (long)b*bB + (long)h*bH;
  const int kchunk = K / KC, kbeg = kc * kchunk;
  const int tm = tid >> 4, tn = tid & 15;
  const int sr = tid >> 4, sc = (tid & 15) * 4;
  float acc1[4][4] = {}, acc2[4][4] = {};
  for (int ks = kbeg; ks < kbeg + kchunk; ks += 64){
    if (ks != kbeg) __syncthreads();
    #pragma unroll
    for (int p = 0; p < 4; ++p){
      const int g = p*16 + sr;
      f32x4 av = *(const f32x4*)&Ab[(long)g*lda + ks + sc];
      As[sc+0][g] = av[0]; As[sc+1][g] = av[1];
      As[sc+2][g] = av[2]; As[sc+3][g] = av[3];
      const int kr = p*16 + sr;
      ushort4 h4 = *(const ushort4*)&b1h[(long)(ks+kr)*ldb + sc];
      ushort4 l4 = *(const ushort4*)&b1l[(long)(ks+kr)*ldb + sc];
      B1s[kr][sc+0] = h2f(h4.x) + h2f(l4.x);
      B1s[kr][sc+1] = h2f(h4.y) + h2f(l4.y);
      B1s[kr][sc+2] = h2f(h4.z) + h2f(l4.z);
      B1s[kr][sc+3] = h2f(h4.w) + h2f(l4.w);
      h4 = *(const ushort4*)&b2h[(long)(ks+kr)*ldb + sc];
      l4 = *(const ushort4*)&b2l[(long)(ks+kr)*ldb + sc];
      B2s[kr][sc+0] = h2f(h4.x) + h2f(l4.x);
      B2s[kr][sc+1] = h2f(h4.y) + h2f(l4.y);
      B2s[kr][sc+2] = h2f(h4.z) + h2f(l4.z);
      B2s[kr][sc+3] = h2f(h4.w) + h2f(l4.w);
    }
    __syncthreads();
    #pragma unroll 4
    for (int k = 0; k < 64; ++k){
      f32x4 a4 = *(const f32x4*)&As[k][tm*4];
      f32x4 b4 = *(const f32x4*)&B1s[k][tn*4];
      f32x4 c4 = *(const f32x4*)&B2s[k][tn*4];
      #pragma unroll
      for (int i = 0; i < 4; ++i)
        #pragma unroll
        for (int j = 0; j < 4; ++j){
          acc1[i][j] += a4[i] * b4[j];
          acc2[i][j] += a4[i] * c4[j];
        }
    }
  }
  const long po = ((long)(kc*nbatch + batch) << 12);
  #pragma unroll
  for (int i = 0; i < 4; ++i){
    f32x4 v1 = { acc1[i][0], acc1[i][1], acc1[i][2], acc1[i][3] };
    f32x4 v2 = { acc2[i][0], acc2[i][1], acc2[i][2], acc2[i][3] };
    *(f32x4*)&P1[po + (tm*4+i)*64 + tn*4] = v1;
    *(f32x4*)&P2[po + (tm*4+i)*64 + tn*4] = v2;
  }
}

// ---------------- sum split-K partials; write fp32 and/or split f16 planes ----------------
__global__ __launch_bounds__(256)
void reduce64(const float* __restrict__ part, float* __restrict__ outf,
              unsigned short* __restrict__ outhi, unsigned short* __restrict__ outlo,
              int n4, int parts)
{
  const int idx = blockIdx.x*256 + threadIdx.x;
  if (idx >= n4) return;
  f32x4 s = ((const f32x4*)part)[idx];
  for (int p = 1; p < parts; ++p) s += ((const f32x4*)part)[(long)p*n4 + idx];
  if (outf) ((f32x4*)outf)[idx] = s;
  if (outhi){
    ushort4 uh, ul;
    split1h(s[0], uh.x, ul.x); split1h(s[1], uh.y, ul.y);
    split1h(s[2], uh.z, ul.z); split1h(s[3], uh.w, ul.w);
    ((ushort4*)outhi)[idx] = uh;
    ((ushort4*)outlo)[idx] = ul;
  }
}

// ---------------- stage 2: 2-pass online softmax(qs.gk^T*scale) -> l_attn + attn_out ----------------
__global__ __launch_bounds__(256)
void stage2(const unsigned short* __restrict__ qhi, const unsigned short* __restrict__ qlo,
            const float* __restrict__ gk, const float* __restrict__ gv,
            float* __restrict__ lattn, float* __restrict__ aout, float scale)
{
  __shared__ f32x4 gkS[1024];   // 64 g x 16 f32x4 (=64 d)
  __shared__ f32x4 gvS[1024];
  const int tid = threadIdx.x;
  const int bh = blockIdx.y;
  const int b = bh >> 4, h = bh & 15;
  const f32x4* gkp = (const f32x4*)(gk + (long)bh*4096);
  const f32x4* gvp = (const f32x4*)(gv + (long)bh*4096);
  #pragma unroll
  for (int i = 0; i < 4; ++i){
    gkS[i*256 + tid] = gkp[i*256 + tid];
    gvS[i*256 + tid] = gvp[i*256 + tid];
  }
  __syncthreads();
  const int l = blockIdx.x*256 + tid;

  const long qoff = ((long)b*2048 + l)*1024 + h*64;
  const unsigned short* qph = qhi + qoff;
  const unsigned short* qpl = qlo + qoff;
  f32x4 qf[16];
  #pragma unroll
  for (int i = 0; i < 8; ++i){
    uint4 uh = ((const uint4*)qph)[i];
    uint4 ul = ((const uint4*)qpl)[i];
    f32x4 t0 = { h2f((unsigned short)(uh.x)) + h2f((unsigned short)(ul.x)),
                 h2f((unsigned short)(uh.x >> 16)) + h2f((unsigned short)(ul.x >> 16)),
                 h2f((unsigned short)(uh.y)) + h2f((unsigned short)(ul.y)),
                 h2f((unsigned short)(uh.y >> 16)) + h2f((unsigned short)(ul.y >> 16)) };
    f32x4 t1 = { h2f((unsigned short)(uh.z)) + h2f((unsigned short)(ul.z)),
                 h2f((unsigned short)(uh.z >> 16)) + h2f((unsigned short)(ul.z >> 16)),
                 h2f((unsigned short)(uh.w)) + h2f((unsigned short)(ul.w)),
                 h2f((unsigned short)(uh.w >> 16)) + h2f((unsigned short)(ul.w >> 16)) };
    qf[2*i+0] = t0; qf[2*i+1] = t1;
  }

  // pass 1: online max + sum (no score array -> no spill)
  float m = -1e30f, sum = 0.f;
  #pragma unroll 4
  for (int g = 0; g < 64; ++g){
    f32x4 a = {0.f,0.f,0.f,0.f};
    #pragma unroll
    for (int d = 0; d < 16; ++d) a += qf[d] * gkS[g*16 + d];
    float s = ((a[0]+a[1]) + (a[2]+a[3])) * scale;
    float mn = fmaxf(m, s);
    sum = sum * __expf(m - mn) + __expf(s - mn);
    m = mn;
  }
  const float inv = 1.0f / sum;

  // pass 2: recompute scores, emit l_attn, accumulate PV
  f32x4 of[16];
  #pragma unroll
  for (int d = 0; d < 16; ++d){ f32x4 z = {0.f,0.f,0.f,0.f}; of[d] = z; }
  float* lp = lattn + ((long)bh*2048 + l)*64;
  #pragma unroll 2
  for (int g4 = 0; g4 < 16; ++g4){
    f32x4 pv;
    #pragma unroll
    for (int j = 0; j < 4; ++j){
      const int g = g4*4 + j;
      f32x4 a = {0.f,0.f,0.f,0.f};
      #pragma unroll
      for (int d = 0; d < 16; ++d) a += qf[d] * gkS[g*16 + d];
      float s = ((a[0]+a[1]) + (a[2]+a[3])) * scale;
      float p = __expf(s - m) * inv;
      pv[j] = p;
      #pragma unroll
      for (int d = 0; d < 16; ++d) of[d] += p * gvS[g*16 + d];
    }
    ((f32x4*)lp)[g4] = pv;
  }
  float* op = aout + qoff;
  #pragma unroll
  for (int i = 0; i < 16; ++i) ((f32x4*)op)[i] = of[i];
}

extern "C" void kernel_launch(void* const* d_in, const int* in_sizes, int n_in,
                              void* d_out, int out_size, void* d_ws, size_t ws_size,
                              hipStream_t stream)
{
  const float* query = (const float*)d_in[0];
  const float* key   = (const float*)d_in[1];
  const float* value = (const float*)d_in[2];
  const unsigned char* mask_raw = (const unsigned char*)d_in[4];
  const float* Wq = (const float*)d_in[6];
  const float* Wk = (const float*)d_in[7];
  const float* Wv = (const float*)d_in[8];
  const float* Wi = (const float*)d_in[9];
  const float* Wo = (const float*)d_in[10];
  float* out0 = (float*)d_out;                  // (B,L,E)
  float* out1 = out0 + 16777216;                // (B,H,L,G)

  // ---- workspace (byte offsets; ~276 MiB) ----
  char* ws = (char*)d_ws;
  unsigned short* WoT_hi = (unsigned short*)(ws + 0);         // 2 MiB each plane
  unsigned short* WoT_lo = (unsigned short*)(ws + (2L<<20));
  unsigned short* WqT_hi = (unsigned short*)(ws + (4L<<20));
  unsigned short* WqT_lo = (unsigned short*)(ws + (6L<<20));
  unsigned short* WkT_hi = (unsigned short*)(ws + (8L<<20));
  unsigned short* WkT_lo = (unsigned short*)(ws + (10L<<20));
  unsigned short* WvT_hi = (unsigned short*)(ws + (12L<<20));
  unsigned short* WvT_lo = (unsigned short*)(ws + (14L<<20));
  unsigned short* WiT_hi = (unsigned short*)(ws + (16L<<20));
  unsigned short* WiT_lo = (unsigned short*)(ws + (18L<<20));
  unsigned short* qs_hi  = (unsigned short*)(ws + (20L<<20)); // 32 MiB each plane
  unsigned short* qs_lo  = (unsigned short*)(ws + (52L<<20));
  unsigned short* kk_hi  = (unsigned short*)(ws + (84L<<20));
  unsigned short* kk_lo  = (unsigned short*)(ws + (116L<<20));
  unsigned short* vs_hi  = (unsigned short*)(ws + (148L<<20));
  unsigned short* vs_lo  = (unsigned short*)(ws + (180L<<20));
  float* scoref = (float*)(ws + (212L<<20));                  // 64 MiB
  // overlays on [WqT_hi .. WiT_lo) = bytes [4,20) MiB, dead after ips GEMM:
  float* part1   = (float*)(ws + (4L<<20));                   // 8 MiB (kc<=4)
  float* part2   = (float*)(ws + (8L<<20));                   // 4 MiB (dual kc=2; part1 uses [4,8))
  unsigned short* gqs_hi = (unsigned short*)(ws + (12L<<20)); // 1 MiB
  unsigned short* gqs_lo = (unsigned short*)(ws + (13L<<20)); // 1 MiB
  float* gk_f    = (float*)(ws + (14L<<20));                  // 2 MiB
  float* gv_f    = (float*)(ws + (16L<<20));                  // 2 MiB
  unsigned char* mask_ws = (unsigned char*)(ws + (18L<<20));  // 16 KiB
  float* attn_out = (float*)kk_hi;                            // 64 MiB (kk planes dead)

  const dim3 blk(256);
  const float scale = 0.125f;   // 1/sqrt(64)

  // 1) weight transposes -> split f16 planes
  transpose_split<<<dim3(16,16), blk, 0, stream>>>(Wq, WqT_hi, WqT_lo, 1024, 1024);
  transpose_split<<<dim3(16,16), blk, 0, stream>>>(Wk, WkT_hi, WkT_lo, 1024, 1024);
  transpose_split<<<dim3(16,16), blk, 0, stream>>>(Wv, WvT_hi, WvT_lo, 1024, 1024);
  transpose_split<<<dim3(16,16), blk, 0, stream>>>(Wi, WiT_hi, WiT_lo, 1024, 1024);
  transpose_split<<<dim3(16,16), blk, 0, stream>>>(Wo, WoT_hi, WoT_lo, 1024, 1024);

  // 2) projections: A = raw fp32 (2-term on-stage), B = weight hi plane
  gemm_sp<128,0,1,1,0><<<dim3(8,128,1), blk, 0, stream>>>(
      query, nullptr, WqT_hi, qs_hi, qs_lo, nullptr,
      1024, 1024,1024,1024, 0,0, 0,0, 0,0, 1, 2048, 1.f);
  gemm_sp<128,0,1,1,0><<<dim3(8,128,1), blk, 0, stream>>>(
      key,   nullptr, WkT_hi, kk_hi, kk_lo, nullptr,
      1024, 1024,1024,1024, 0,0, 0,0, 0,0, 1, 2048, 1.f);
  gemm_sp<128,0,1,1,0><<<dim3(8,128,1), blk, 0, stream>>>(
      value, nullptr, WvT_hi, vs_hi, vs_lo, nullptr,
      1024, 1024,1024,1024, 0,0, 0,0, 0,0, 1, 2048, 1.f);

  // 3) ipsT[b][hg][l] = WiT @ q[b]^T -> fp32; A = WiT planes (2-term), B = query cvt-on-stage
  gemm_sp<128,1,0,0,0><<<dim3(16,8,8), blk, 0, stream>>>(
      WiT_hi, WiT_lo, query, scoref, nullptr, nullptr,
      1024, 1024,1024,2048, 0,0, 2097152L,0, 2097152L,0, 1, 2048, 1.f);
  mask_norm<<<1, blk, 0, stream>>>(mask_raw, mask_ws, 16384);
  softmax_inplace<<<8192, blk, 0, stream>>>(scoref, 2048);

  // 4) gqs[bh] = wts[bh](64xL) @ qs[bh](Lx64) -> split planes (kc=4)
  einsum64<<<dim3(4,128), blk, 0, stream>>>(scoref, qs_hi, qs_lo, part1,
      2048, 4, 2048, 1024, 2097152L, 131072L, 2097152L, 64L, 16, 128);
  reduce64<<<512, blk, 0, stream>>>(part1, nullptr, gqs_hi, gqs_lo, 131072, 4);

  // 5) g_scores[bh] = gqs@kk^T * scale, mask -> fp32; softmax in place -> g_attn
  gemm_sp<64,1,1,0,1><<<dim3(16,1,128), blk, 0, stream>>>(
      gqs_hi, gqs_lo, kk_hi, scoref, nullptr, mask_ws,
      64, 64,1024,2048, 65536L,4096L, 2097152L,64L, 2097152L,131072L, 16, 2048, scale);
  softmax_inplace<<<8192, blk, 0, stream>>>(scoref, 2048);

  // 6) gk/gv[bh] = g_attn[bh](64xS) @ {kk,vs}[bh](Sx64) -> fused dual (kc=2)
  einsum64_dual<<<dim3(2,128), blk, 0, stream>>>(scoref, kk_hi, kk_lo, vs_hi, vs_lo,
      part1, part2, 2048, 2, 2048, 1024, 2097152L, 131072L, 2097152L, 64L, 16, 128);
  reduce64<<<512, blk, 0, stream>>>(part1, gk_f, nullptr, nullptr, 131072, 2);
  reduce64<<<512, blk, 0, stream>>>(part2, gv_f, nullptr, nullptr, 131072, 2);

  // 7) stage 2: l_attn (out1) + attn_out fp32 (over dead kk planes)
  stage2<<<dim3(8,128), blk, 0, stream>>>(qs_hi, qs_lo, gk_f, gv_f, out1, attn_out, scale);

  // 8) out0 = attn_out @ Wo (A 2-term on-stage, B = WoT hi plane)
  gemm_sp<128,0,1,0,0><<<dim3(8,128,1), blk, 0, stream>>>(
      attn_out, nullptr, WoT_hi, out0, nullptr, nullptr,
      1024, 1024,1024,1024, 0,0, 0,0, 0,0, 1, 2048, 1.f);

  (void)in_sizes; (void)n_in; (void)out_size; (void)ws_size;
}

// Round 5
// 882.897 us; speedup vs baseline: 1.3686x; 1.1426x over previous
//
#include <hip/hip_runtime.h>

// EGA multi-headed attention, MI355X/gfx950.
// Round 5: stage2 -> batched MFMA (S=qs@gk^T, softmax(G=64), O=P@gv) writing
//          attn planes directly; query pre-split once (AM=1 fast staging for
//          q-proj and ips); gqs einsum split-K 4->2.
// Dims fixed: B=8, L=S=2048, E=1024, H=16, G=64, Ek=Ev=64, KD=VD=1024.

typedef float f32x4 __attribute__((ext_vector_type(4)));
typedef _Float16 f16x8 __attribute__((ext_vector_type(8)));
typedef unsigned short u16;

#define DEV static __device__ __forceinline__

DEV u16 f2h(float x){
  _Float16 h = (_Float16)x;
  return __builtin_bit_cast(u16, h);
}
DEV float h2f(u16 u){
  return (float)__builtin_bit_cast(_Float16, u);
}
DEV void split1h(float x, u16 &h, u16 &l){
  h = f2h(x);
  l = f2h(x - h2f(h));
}
DEV unsigned pk2h(float a, float b){
  return (unsigned)f2h(a) | ((unsigned)f2h(b) << 16);
}
DEV void split2pkh(float a, float b, unsigned &h, unsigned &l){
  u16 ha, la, hb, lb;
  split1h(a, ha, la); split1h(b, hb, lb);
  h = (unsigned)ha | ((unsigned)hb << 16);
  l = (unsigned)la | ((unsigned)lb << 16);
}

// ---------------- mask dtype sniff + normalize to uchar ----------------
__global__ __launch_bounds__(256)
void mask_norm(const unsigned char* __restrict__ src, unsigned char* __restrict__ dst, int n)
{
  const unsigned* w = (const unsigned*)src;
  const int tid = threadIdx.x;
  int local = 0;
  for (int i = tid; i < n/4; i += 256){
    unsigned v = w[i];
    if (v == 0x3F800000u) local |= 2;
    else if (v > 1u)      local |= 1;
  }
  __shared__ int red[256];
  red[tid] = local;
  __syncthreads();
  for (int s = 128; s; s >>= 1){
    if (tid < s) red[tid] |= red[tid+s];
    __syncthreads();
  }
  const int r = red[0];
  const int mode = (r & 2) ? 2 : ((r & 1) ? 1 : 0);   // 2=f32, 1=u8, 0=i32
  for (int i = tid; i < n; i += 256){
    unsigned char v;
    if (mode == 1) v = src[i] ? 1 : 0;
    else           v = w[i]   ? 1 : 0;
    dst[i] = v;
  }
}

// ---------------- fp32 -> f16 hi/lo planes (flat, 8 elems/thread) ----------------
__global__ __launch_bounds__(256)
void conv_split(const float* __restrict__ x, u16* __restrict__ hi, u16* __restrict__ lo, int n8)
{
  const int i = blockIdx.x*256 + threadIdx.x;
  if (i >= n8) return;
  f32x4 a = ((const f32x4*)x)[2*i], b = ((const f32x4*)x)[2*i+1];
  uint4 uh, ul;
  split2pkh(a[0], a[1], uh.x, ul.x);
  split2pkh(a[2], a[3], uh.y, ul.y);
  split2pkh(b[0], b[1], uh.z, ul.z);
  split2pkh(b[2], b[3], uh.w, ul.w);
  ((uint4*)hi)[i] = uh;
  ((uint4*)lo)[i] = ul;
}

// ---------------- 1024x1024 transpose, fp32 -> split f16 planes ----------------
__global__ __launch_bounds__(256)
void transpose_split(const float* __restrict__ Wsrc,
                     u16* __restrict__ Whi, u16* __restrict__ Wlo,
                     int Kd, int Nd)
{
  __shared__ float t[64][65];
  const int tid = threadIdx.x;
  const int n0 = blockIdx.x * 64, k0 = blockIdx.y * 64;
  #pragma unroll
  for (int it = 0; it < 16; ++it){
    int e = it*256 + tid, r = e >> 6, c = e & 63;
    t[r][c] = Wsrc[(long)(k0+r)*Nd + (n0+c)];
  }
  __syncthreads();
  #pragma unroll
  for (int it = 0; it < 16; ++it){
    int e = it*256 + tid, r = e >> 6, c = e & 63;
    u16 h, l;
    split1h(t[c][r], h, l);
    const long idx = (long)(n0+r)*Kd + (k0+c);
    Whi[idx] = h; Wlo[idx] = l;
  }
}

// ---------------- f16 2-term MFMA GEMM: C[m,n] = sum_k A[m,k]*Bt[n,k] ----------------
// A: 2 planes (AM=0: fp32 split-on-stage; AM=1: pre-split planes Ap/Ap2).
// B: 1 plane  (BMODE=1: pre-split hi plane).
// CM: 0 = fp32 out; 1 = split f16 planes out.  EPI==1: scale+mask epilogue.
template<int TM, int AM, int BMODE, int CM, int EPI>
__global__ __launch_bounds__(256)
void gemm_sp(const void* __restrict__ Ap, const void* __restrict__ Ap2,
             const void* __restrict__ Bp,
             void* __restrict__ Cp, void* __restrict__ Cp2,
             const unsigned char* __restrict__ maskp,
             int K, int lda, int ldb, int ldc,
             long aB, long aH, long bB, long bH, long cB, long cH,
             int H2, int Ssz, float scale)
{
  constexpr int BN = 128, BK = 32, PAD = 8;
  constexpr int WM = TM/2, WN = BN/2;
  constexpr int FM = WM/16, FN = WN/16;
  __shared__ __align__(16) u16 AhS[TM][BK+PAD];
  __shared__ __align__(16) u16 AlS[TM][BK+PAD];
  __shared__ __align__(16) u16 BhS[BN][BK+PAD];

  const int tid = threadIdx.x;
  const int batch = blockIdx.z;
  const int b = batch / H2, h = batch - b*H2;
  const long aOff = (long)b*aB + (long)h*aH;
  const long bOff = (long)b*bB + (long)h*bH;
  const long cOff = (long)b*cB + (long)h*cH;
  const int nBase = blockIdx.x * BN;
  const int mBase = blockIdx.y * TM;
  const int wave = tid >> 6, lane = tid & 63;
  const int wm = wave >> 1, wn = wave & 1;
  const int srow = tid >> 2, scol = (tid & 3) * 8;

  f32x4 acc[FM][FN] = {};

  for (int k0 = 0; k0 < K; k0 += BK){
    if (k0) __syncthreads();
    #pragma unroll
    for (int c = 0; c < TM/64; ++c){
      const int row = c*64 + srow;
      const long g = aOff + (long)(mBase+row)*lda + (k0 + scol);
      if constexpr (AM == 0){
        const float* Af = (const float*)Ap;
        f32x4 f0 = *(const f32x4*)(Af + g);
        f32x4 f1 = *(const f32x4*)(Af + g + 4);
        uint4 uh, ul;
        split2pkh(f0[0], f0[1], uh.x, ul.x);
        split2pkh(f0[2], f0[3], uh.y, ul.y);
        split2pkh(f1[0], f1[1], uh.z, ul.z);
        split2pkh(f1[2], f1[3], uh.w, ul.w);
        *(uint4*)&AhS[row][scol] = uh;
        *(uint4*)&AlS[row][scol] = ul;
      } else {
        *(uint4*)&AhS[row][scol] = *(const uint4*)((const u16*)Ap  + g);
        *(uint4*)&AlS[row][scol] = *(const uint4*)((const u16*)Ap2 + g);
      }
    }
    #pragma unroll
    for (int c = 0; c < BN/64; ++c){
      const int row = c*64 + srow;
      const long g = bOff + (long)(nBase+row)*ldb + (k0 + scol);
      *(uint4*)&BhS[row][scol] = *(const uint4*)((const u16*)Bp + g);
    }
    __syncthreads();
    f16x8 ah[FM], al[FM], bh[FN];
    #pragma unroll
    for (int mi = 0; mi < FM; ++mi){
      ah[mi] = *(const f16x8*)&AhS[wm*WM + mi*16 + (lane & 15)][(lane >> 4) * 8];
      al[mi] = *(const f16x8*)&AlS[wm*WM + mi*16 + (lane & 15)][(lane >> 4) * 8];
    }
    #pragma unroll
    for (int ni = 0; ni < FN; ++ni)
      bh[ni] = *(const f16x8*)&BhS[wn*WN + ni*16 + (lane & 15)][(lane >> 4) * 8];
    #pragma unroll
    for (int mi = 0; mi < FM; ++mi)
      #pragma unroll
      for (int ni = 0; ni < FN; ++ni){
        acc[mi][ni] = __builtin_amdgcn_mfma_f32_16x16x32_f16(ah[mi], bh[ni], acc[mi][ni], 0, 0, 0);
        acc[mi][ni] = __builtin_amdgcn_mfma_f32_16x16x32_f16(al[mi], bh[ni], acc[mi][ni], 0, 0, 0);
      }
  }

  const int cr = (lane >> 4) * 4, cc = lane & 15;
  #pragma unroll
  for (int mi = 0; mi < FM; ++mi)
    #pragma unroll
    for (int ni = 0; ni < FN; ++ni)
      #pragma unroll
      for (int r = 0; r < 4; ++r){
        const int row = mBase + wm*WM + mi*16 + cr + r;
        const int col = nBase + wn*WN + ni*16 + cc;
        float v = acc[mi][ni][r];
        if constexpr (EPI == 1){
          v *= scale;
          if (maskp[(long)b*Ssz + col]) v = -1e9f;
        }
        const long ci = cOff + (long)row*ldc + col;
        if constexpr (CM == 0){
          ((float*)Cp)[ci] = v;
        } else {
          u16 hh, ll;
          split1h(v, hh, ll);
          ((u16*)Cp)[ci]  = hh;
          ((u16*)Cp2)[ci] = ll;
        }
      }
}

// ---------------- row softmax (width 2048), fp32 in-place ----------------
__global__ __launch_bounds__(256)
void softmax_inplace(float* __restrict__ data, int Wd)
{
  float* rp = data + (long)blockIdx.x * Wd;
  const int tid = threadIdx.x;
  const int lane = tid & 63, wv = tid >> 6;
  f32x4 v0 = ((const f32x4*)rp)[tid*2];
  f32x4 v1 = ((const f32x4*)rp)[tid*2+1];
  float m = fmaxf(fmaxf(fmaxf(v0[0],v0[1]),fmaxf(v0[2],v0[3])),
                  fmaxf(fmaxf(v1[0],v1[1]),fmaxf(v1[2],v1[3])));
  #pragma unroll
  for (int off = 32; off; off >>= 1) m = fmaxf(m, __shfl_xor(m, off));
  __shared__ float rm[4], rs[4];
  if (lane == 0) rm[wv] = m;
  __syncthreads();
  m = fmaxf(fmaxf(rm[0],rm[1]), fmaxf(rm[2],rm[3]));
  f32x4 e0, e1;
  #pragma unroll
  for (int i = 0; i < 4; ++i){ e0[i] = __expf(v0[i]-m); e1[i] = __expf(v1[i]-m); }
  float s = (e0[0]+e0[1]+e0[2]+e0[3]) + (e1[0]+e1[1]+e1[2]+e1[3]);
  #pragma unroll
  for (int off = 32; off; off >>= 1) s += __shfl_xor(s, off);
  if (lane == 0) rs[wv] = s;
  __syncthreads();
  s = (rs[0]+rs[1]) + (rs[2]+rs[3]);
  const float inv = 1.0f / s;
  ((f32x4*)rp)[tid*2]   = e0 * inv;
  ((f32x4*)rp)[tid*2+1] = e1 * inv;
}

// ---------------- batched 64xK @ Kx64 einsum, fp32 A x f16 plane-pair B, split-K ----------------
__global__ __launch_bounds__(256)
void einsum64(const float* __restrict__ A,
              const u16* __restrict__ Bhip, const u16* __restrict__ Blop,
              float* __restrict__ Cpart,
              int K, int KC, int lda, int ldb,
              long aB, long aH, long bB, long bH, int H2, int nbatch)
{
  __shared__ float As[64][68];
  __shared__ float Bs[64][68];
  const int tid = threadIdx.x;
  const int kc = blockIdx.x, batch = blockIdx.y;
  const int b = batch / H2, h = batch - b*H2;
  const float* Ab = A + (long)b*aB + (long)h*aH;
  const u16* Bh = Bhip + (long)b*bB + (long)h*bH;
  const u16* Bl = Blop + (long)b*bB + (long)h*bH;
  const int kchunk = K / KC, kbeg = kc * kchunk;
  const int tm = tid >> 4, tn = tid & 15;
  const int sr = tid >> 4, sc = (tid & 15) * 4;
  float acc[4][4] = {};
  for (int ks = kbeg; ks < kbeg + kchunk; ks += 64){
    if (ks != kbeg) __syncthreads();
    #pragma unroll
    for (int p = 0; p < 4; ++p){
      const int g = p*16 + sr;
      f32x4 av = *(const f32x4*)&Ab[(long)g*lda + ks + sc];
      As[sc+0][g] = av[0]; As[sc+1][g] = av[1];
      As[sc+2][g] = av[2]; As[sc+3][g] = av[3];
      const int kr = p*16 + sr;
      ushort4 h4 = *(const ushort4*)&Bh[(long)(ks+kr)*ldb + sc];
      ushort4 l4 = *(const ushort4*)&Bl[(long)(ks+kr)*ldb + sc];
      Bs[kr][sc+0] = h2f(h4.x) + h2f(l4.x);
      Bs[kr][sc+1] = h2f(h4.y) + h2f(l4.y);
      Bs[kr][sc+2] = h2f(h4.z) + h2f(l4.z);
      Bs[kr][sc+3] = h2f(h4.w) + h2f(l4.w);
    }
    __syncthreads();
    #pragma unroll 8
    for (int k = 0; k < 64; ++k){
      f32x4 a4 = *(const f32x4*)&As[k][tm*4];
      f32x4 b4 = *(const f32x4*)&Bs[k][tn*4];
      #pragma unroll
      for (int i = 0; i < 4; ++i)
        #pragma unroll
        for (int j = 0; j < 4; ++j)
          acc[i][j] += a4[i] * b4[j];
    }
  }
  float* outp = Cpart + ((long)(kc*nbatch + batch) << 12);
  #pragma unroll
  for (int i = 0; i < 4; ++i){
    f32x4 v = { acc[i][0], acc[i][1], acc[i][2], acc[i][3] };
    *(f32x4*)&outp[(tm*4+i)*64 + tn*4] = v;
  }
}

// ---------------- dual einsum: shared A, two B plane-pairs (kk & vs) ----------------
__global__ __launch_bounds__(256)
void einsum64_dual(const float* __restrict__ A,
                   const u16* __restrict__ B1h, const u16* __restrict__ B1l,
                   const u16* __restrict__ B2h, const u16* __restrict__ B2l,
                   float* __restrict__ P1, float* __restrict__ P2,
                   int K, int KC, int lda, int ldb,
                   long aB, long aH, long bB, long bH, int H2, int nbatch)
{
  __shared__ float As[64][68];
  __shared__ float B1s[64][68];
  __shared__ float B2s[64][68];
  const int tid = threadIdx.x;
  const int kc = blockIdx.x, batch = blockIdx.y;
  const int b = batch / H2, h = batch - b*H2;
  const float* Ab = A + (long)b*aB + (long)h*aH;
  const u16* b1h = B1h + (long)b*bB + (long)h*bH;
  const u16* b1l = B1l + (long)b*bB + (long)h*bH;
  const u16* b2h = B2h + (long)b*bB + (long)h*bH;
  const u16* b2l = B2l + (long)b*bB + (long)h*bH;
  const int kchunk = K / KC, kbeg = kc * kchunk;
  const int tm = tid >> 4, tn = tid & 15;
  const int sr = tid >> 4, sc = (tid & 15) * 4;
  float acc1[4][4] = {}, acc2[4][4] = {};
  for (int ks = kbeg; ks < kbeg + kchunk; ks += 64){
    if (ks != kbeg) __syncthreads();
    #pragma unroll
    for (int p = 0; p < 4; ++p){
      const int g = p*16 + sr;
      f32x4 av = *(const f32x4*)&Ab[(long)g*lda + ks + sc];
      As[sc+0][g] = av[0]; As[sc+1][g] = av[1];
      As[sc+2][g] = av[2]; As[sc+3][g] = av[3];
      const int kr = p*16 + sr;
      ushort4 h4 = *(const ushort4*)&b1h[(long)(ks+kr)*ldb + sc];
      ushort4 l4 = *(const ushort4*)&b1l[(long)(ks+kr)*ldb + sc];
      B1s[kr][sc+0] = h2f(h4.x) + h2f(l4.x);
      B1s[kr][sc+1] = h2f(h4.y) + h2f(l4.y);
      B1s[kr][sc+2] = h2f(h4.z) + h2f(l4.z);
      B1s[kr][sc+3] = h2f(h4.w) + h2f(l4.w);
      h4 = *(const ushort4*)&b2h[(long)(ks+kr)*ldb + sc];
      l4 = *(const ushort4*)&b2l[(long)(ks+kr)*ldb + sc];
      B2s[kr][sc+0] = h2f(h4.x) + h2f(l4.x);
      B2s[kr][sc+1] = h2f(h4.y) + h2f(l4.y);
      B2s[kr][sc+2] = h2f(h4.z) + h2f(l4.z);
      B2s[kr][sc+3] = h2f(h4.w) + h2f(l4.w);
    }
    __syncthreads();
    #pragma unroll 4
    for (int k = 0; k < 64; ++k){
      f32x4 a4 = *(const f32x4*)&As[k][tm*4];
      f32x4 b4 = *(const f32x4*)&B1s[k][tn*4];
      f32x4 c4 = *(const f32x4*)&B2s[k][tn*4];
      #pragma unroll
      for (int i = 0; i < 4; ++i)
        #pragma unroll
        for (int j = 0; j < 4; ++j){
          acc1[i][j] += a4[i] * b4[j];
          acc2[i][j] += a4[i] * c4[j];
        }
    }
  }
  const long po = ((long)(kc*nbatch + batch) << 12);
  #pragma unroll
  for (int i = 0; i < 4; ++i){
    f32x4 v1 = { acc1[i][0], acc1[i][1], acc1[i][2], acc1[i][3] };
    f32x4 v2 = { acc2[i][0], acc2[i][1], acc2[i][2], acc2[i][3] };
    *(f32x4*)&P1[po + (tm*4+i)*64 + tn*4] = v1;
    *(f32x4*)&P2[po + (tm*4+i)*64 + tn*4] = v2;
  }
}

// ---------------- sum split-K partials -> split f16 planes ----------------
__global__ __launch_bounds__(256)
void reduce64(const float* __restrict__ part,
              u16* __restrict__ outhi, u16* __restrict__ outlo,
              int n4, int parts)
{
  const int idx = blockIdx.x*256 + threadIdx.x;
  if (idx >= n4) return;
  f32x4 s = ((const f32x4*)part)[idx];
  for (int p = 1; p < parts; ++p) s += ((const f32x4*)part)[(long)p*n4 + idx];
  ushort4 uh, ul;
  split1h(s[0], uh.x, ul.x); split1h(s[1], uh.y, ul.y);
  split1h(s[2], uh.z, ul.z); split1h(s[3], uh.w, ul.w);
  ((ushort4*)outhi)[idx] = uh;
  ((ushort4*)outlo)[idx] = ul;
}

// ---------------- stage 2, MFMA: S=qs@gk^T -> softmax(G=64) -> l_attn; O=P@gv -> attn planes ----
// grid (L/128, B*H), block 256 (4 waves x 32 rows).
__global__ __launch_bounds__(256)
void stage2_mfma(const u16* __restrict__ qhi, const u16* __restrict__ qlo,
                 const u16* __restrict__ gkh_g, const u16* __restrict__ gkl_g,
                 const u16* __restrict__ gvh_g, const u16* __restrict__ gvl_g,
                 float* __restrict__ lattn, u16* __restrict__ ahi, u16* __restrict__ alo,
                 float scale)
{
  __shared__ __align__(16) u16 Ah[128][72];   // qs tile hi, then P hi
  __shared__ __align__(16) u16 Al[128][72];   // qs tile lo, then P lo
  __shared__ __align__(16) u16 Bh[64][72];    // gk hi, then gv^T hi
  __shared__ __align__(16) u16 Bl[64][72];    // gk lo, then gv^T lo
  const int tid = threadIdx.x;
  const int bh = blockIdx.y;
  const int b = bh >> 4, h = bh & 15;
  const int l0 = blockIdx.x * 128;
  const int wm = tid >> 6, lane = tid & 63;

  // stage qs tile planes (128 x 64)
  const long qbase = ((long)b*2048 + l0)*1024 + h*64;
  #pragma unroll
  for (int it = 0; it < 4; ++it){
    const int e = it*256 + tid, row = e >> 3, s = e & 7;
    const long g = qbase + (long)row*1024 + s*8;
    *(uint4*)&Ah[row][s*8] = *(const uint4*)(qhi + g);
    *(uint4*)&Al[row][s*8] = *(const uint4*)(qlo + g);
  }
  // stage gk planes (64 x 64, row-major g,d)
  const long gb = (long)bh * 4096;
  #pragma unroll
  for (int it = 0; it < 2; ++it){
    const int e = it*256 + tid, gr = e >> 3, s = e & 7;
    *(uint4*)&Bh[gr][s*8] = *(const uint4*)(gkh_g + gb + gr*64 + s*8);
    *(uint4*)&Bl[gr][s*8] = *(const uint4*)(gkl_g + gb + gr*64 + s*8);
  }
  __syncthreads();

  // S = qs @ gk^T  (3-term f16)
  f32x4 acc[2][4] = {};
  #pragma unroll
  for (int k0 = 0; k0 < 64; k0 += 32){
    f16x8 a_h[2], a_l[2], b_h[4], b_l[4];
    #pragma unroll
    for (int mi = 0; mi < 2; ++mi){
      const int row = wm*32 + mi*16 + (lane & 15);
      a_h[mi] = *(const f16x8*)&Ah[row][k0 + (lane >> 4)*8];
      a_l[mi] = *(const f16x8*)&Al[row][k0 + (lane >> 4)*8];
    }
    #pragma unroll
    for (int ni = 0; ni < 4; ++ni){
      const int nr = ni*16 + (lane & 15);
      b_h[ni] = *(const f16x8*)&Bh[nr][k0 + (lane >> 4)*8];
      b_l[ni] = *(const f16x8*)&Bl[nr][k0 + (lane >> 4)*8];
    }
    #pragma unroll
    for (int mi = 0; mi < 2; ++mi)
      #pragma unroll
      for (int ni = 0; ni < 4; ++ni){
        acc[mi][ni] = __builtin_amdgcn_mfma_f32_16x16x32_f16(a_h[mi], b_h[ni], acc[mi][ni], 0, 0, 0);
        acc[mi][ni] = __builtin_amdgcn_mfma_f32_16x16x32_f16(a_l[mi], b_h[ni], acc[mi][ni], 0, 0, 0);
        acc[mi][ni] = __builtin_amdgcn_mfma_f32_16x16x32_f16(a_h[mi], b_l[ni], acc[mi][ni], 0, 0, 0);
      }
  }
  __syncthreads();   // all LDS reads of the S phase complete

  // stage gv^T planes into Bh/Bl (gk is dead)
  #pragma unroll
  for (int it = 0; it < 4; ++it){
    const int e = it*256 + tid;            // 1024 ushort4 per plane
    const int gr = e >> 4, d0 = (e & 15) * 4;
    ushort4 vh = *(const ushort4*)(gvh_g + gb + gr*64 + d0);
    ushort4 vl = *(const ushort4*)(gvl_g + gb + gr*64 + d0);
    Bh[d0+0][gr] = vh.x; Bh[d0+1][gr] = vh.y; Bh[d0+2][gr] = vh.z; Bh[d0+3][gr] = vh.w;
    Bl[d0+0][gr] = vl.x; Bl[d0+1][gr] = vl.y; Bl[d0+2][gr] = vl.z; Bl[d0+3][gr] = vl.w;
  }

  // softmax over g per row; emit l_attn fp32; P planes into Ah/Al (own rows only)
  #pragma unroll
  for (int mi = 0; mi < 2; ++mi){
    #pragma unroll
    for (int r = 0; r < 4; ++r){
      float v0 = acc[mi][0][r]*scale, v1 = acc[mi][1][r]*scale;
      float v2 = acc[mi][2][r]*scale, v3 = acc[mi][3][r]*scale;
      float mx = fmaxf(fmaxf(v0,v1), fmaxf(v2,v3));
      #pragma unroll
      for (int off = 1; off < 16; off <<= 1) mx = fmaxf(mx, __shfl_xor(mx, off, 16));
      float e0 = __expf(v0-mx), e1 = __expf(v1-mx), e2 = __expf(v2-mx), e3 = __expf(v3-mx);
      float sum = (e0+e1) + (e2+e3);
      #pragma unroll
      for (int off = 1; off < 16; off <<= 1) sum += __shfl_xor(sum, off, 16);
      const float inv = 1.0f / sum;
      e0 *= inv; e1 *= inv; e2 *= inv; e3 *= inv;
      const int lrow = wm*32 + mi*16 + (lane >> 4)*4 + r;
      float* lp = lattn + ((long)bh*2048 + l0 + lrow)*64 + (lane & 15);
      lp[0] = e0; lp[16] = e1; lp[32] = e2; lp[48] = e3;
      u16 hh, ll;
      split1h(e0, hh, ll); Ah[lrow][ 0 + (lane&15)] = hh; Al[lrow][ 0 + (lane&15)] = ll;
      split1h(e1, hh, ll); Ah[lrow][16 + (lane&15)] = hh; Al[lrow][16 + (lane&15)] = ll;
      split1h(e2, hh, ll); Ah[lrow][32 + (lane&15)] = hh; Al[lrow][32 + (lane&15)] = ll;
      split1h(e3, hh, ll); Ah[lrow][48 + (lane&15)] = hh; Al[lrow][48 + (lane&15)] = ll;
    }
  }
  __syncthreads();

  // O = P @ gv  (A = P planes, B = gv^T planes; 3-term)
  f32x4 o[2][4] = {};
  #pragma unroll
  for (int k0 = 0; k0 < 64; k0 += 32){
    f16x8 p_h[2], p_l[2], b_h[4], b_l[4];
    #pragma unroll
    for (int mi = 0; mi < 2; ++mi){
      const int row = wm*32 + mi*16 + (lane & 15);
      p_h[mi] = *(const f16x8*)&Ah[row][k0 + (lane >> 4)*8];
      p_l[mi] = *(const f16x8*)&Al[row][k0 + (lane >> 4)*8];
    }
    #pragma unroll
    for (int ni = 0; ni < 4; ++ni){
      const int nr = ni*16 + (lane & 15);
      b_h[ni] = *(const f16x8*)&Bh[nr][k0 + (lane >> 4)*8];
      b_l[ni] = *(const f16x8*)&Bl[nr][k0 + (lane >> 4)*8];
    }
    #pragma unroll
    for (int mi = 0; mi < 2; ++mi)
      #pragma unroll
      for (int ni = 0; ni < 4; ++ni){
        o[mi][ni] = __builtin_amdgcn_mfma_f32_16x16x32_f16(p_h[mi], b_h[ni], o[mi][ni], 0, 0, 0);
        o[mi][ni] = __builtin_amdgcn_mfma_f32_16x16x32_f16(p_l[mi], b_h[ni], o[mi][ni], 0, 0, 0);
        o[mi][ni] = __builtin_amdgcn_mfma_f32_16x16x32_f16(p_h[mi], b_l[ni], o[mi][ni], 0, 0, 0);
      }
  }

  // store attn planes
  #pragma unroll
  for (int mi = 0; mi < 2; ++mi)
    #pragma unroll
    for (int ni = 0; ni < 4; ++ni)
      #pragma unroll
      for (int r = 0; r < 4; ++r){
        const int lrow = wm*32 + mi*16 + (lane >> 4)*4 + r;
        const int d = ni*16 + (lane & 15);
        u16 hh, ll;
        split1h(o[mi][ni][r], hh, ll);
        const long oidx = ((long)b*2048 + l0 + lrow)*1024 + h*64 + d;
        ahi[oidx] = hh; alo[oidx] = ll;
      }
}

extern "C" void kernel_launch(void* const* d_in, const int* in_sizes, int n_in,
                              void* d_out, int out_size, void* d_ws, size_t ws_size,
                              hipStream_t stream)
{
  const float* query = (const float*)d_in[0];
  const float* key   = (const float*)d_in[1];
  const float* value = (const float*)d_in[2];
  const unsigned char* mask_raw = (const unsigned char*)d_in[4];
  const float* Wq = (const float*)d_in[6];
  const float* Wk = (const float*)d_in[7];
  const float* Wv = (const float*)d_in[8];
  const float* Wi = (const float*)d_in[9];
  const float* Wo = (const float*)d_in[10];
  float* out0 = (float*)d_out;                  // (B,L,E)
  float* out1 = out0 + 16777216;                // (B,H,L,G)

  // ---- workspace (byte offsets; ~276 MiB) ----
  char* ws = (char*)d_ws;
  u16* WoT_hi = (u16*)(ws + 0);           // 2 MiB each plane
  u16* WoT_lo = (u16*)(ws + (2L<<20));
  u16* WqT_hi = (u16*)(ws + (4L<<20));
  u16* WqT_lo = (u16*)(ws + (6L<<20));
  u16* WkT_hi = (u16*)(ws + (8L<<20));
  u16* WkT_lo = (u16*)(ws + (10L<<20));
  u16* WvT_hi = (u16*)(ws + (12L<<20));
  u16* WvT_lo = (u16*)(ws + (14L<<20));
  u16* WiT_hi = (u16*)(ws + (16L<<20));
  u16* WiT_lo = (u16*)(ws + (18L<<20));
  u16* qs_hi  = (u16*)(ws + (20L<<20));   // 32 MiB each plane
  u16* qs_lo  = (u16*)(ws + (52L<<20));
  u16* kk_hi  = (u16*)(ws + (84L<<20));
  u16* kk_lo  = (u16*)(ws + (116L<<20));
  u16* vs_hi  = (u16*)(ws + (148L<<20));
  u16* vs_lo  = (u16*)(ws + (180L<<20));
  float* scoref = (float*)(ws + (212L<<20));               // 64 MiB
  // query input planes live in the kk region BEFORE the kk projection runs
  u16* qp_hi = kk_hi;
  u16* qp_lo = kk_lo;
  // overlays on [4,20) MiB (Wq..Wi planes), dead after the ips GEMM:
  float* part1   = (float*)(ws + (4L<<20));                // 4 MiB (kc=2)
  float* part2   = (float*)(ws + (8L<<20));                // 4 MiB
  u16* gqs_hi = (u16*)(ws + (12L<<20));                    // 1 MiB each
  u16* gqs_lo = (u16*)(ws + (13L<<20));
  u16* gk_hi  = (u16*)(ws + (14L<<20));
  u16* gk_lo  = (u16*)(ws + (15L<<20));
  u16* gv_hi  = (u16*)(ws + (16L<<20));
  u16* gv_lo  = (u16*)(ws + (17L<<20));
  unsigned char* mask_ws = (unsigned char*)(ws + (18L<<20)); // 16 KiB
  // attn planes overlay kk planes (dead after the dual einsum)
  u16* attn_hi = kk_hi;
  u16* attn_lo = kk_lo;

  const dim3 blk(256);
  const float scale = 0.125f;   // 1/sqrt(64)

  // 1) weight transposes -> split f16 planes
  transpose_split<<<dim3(16,16), blk, 0, stream>>>(Wq, WqT_hi, WqT_lo, 1024, 1024);
  transpose_split<<<dim3(16,16), blk, 0, stream>>>(Wk, WkT_hi, WkT_lo, 1024, 1024);
  transpose_split<<<dim3(16,16), blk, 0, stream>>>(Wv, WvT_hi, WvT_lo, 1024, 1024);
  transpose_split<<<dim3(16,16), blk, 0, stream>>>(Wi, WiT_hi, WiT_lo, 1024, 1024);
  transpose_split<<<dim3(16,16), blk, 0, stream>>>(Wo, WoT_hi, WoT_lo, 1024, 1024);

  // 2) pre-split query into planes (lives in kk region until kk projection)
  conv_split<<<8192, blk, 0, stream>>>(query, qp_hi, qp_lo, 2097152);

  // 3) qs projection: A = query planes (copy staging), B = Wq hi plane
  gemm_sp<128,1,1,1,0><<<dim3(8,128,1), blk, 0, stream>>>(
      qp_hi, qp_lo, WqT_hi, qs_hi, qs_lo, nullptr,
      1024, 1024,1024,1024, 0,0, 0,0, 0,0, 1, 2048, 1.f);

  // 4) ipsT[b][hg][l] = WiT @ q[b]^T -> fp32 (A = WiT planes, B = query hi plane)
  gemm_sp<128,1,1,0,0><<<dim3(16,8,8), blk, 0, stream>>>(
      WiT_hi, WiT_lo, qp_hi, scoref, nullptr, nullptr,
      1024, 1024,1024,2048, 0,0, 2097152L,0, 2097152L,0, 1, 2048, 1.f);
  mask_norm<<<1, blk, 0, stream>>>(mask_raw, mask_ws, 16384);
  softmax_inplace<<<8192, blk, 0, stream>>>(scoref, 2048);

  // 5) kk / vs projections (query planes now dead; kk overwrites them)
  gemm_sp<128,0,1,1,0><<<dim3(8,128,1), blk, 0, stream>>>(
      key,   nullptr, WkT_hi, kk_hi, kk_lo, nullptr,
      1024, 1024,1024,1024, 0,0, 0,0, 0,0, 1, 2048, 1.f);
  gemm_sp<128,0,1,1,0><<<dim3(8,128,1), blk, 0, stream>>>(
      value, nullptr, WvT_hi, vs_hi, vs_lo, nullptr,
      1024, 1024,1024,1024, 0,0, 0,0, 0,0, 1, 2048, 1.f);

  // 6) gqs[bh] = wts[bh](64xL) @ qs[bh](Lx64) -> split planes (kc=2)
  einsum64<<<dim3(2,128), blk, 0, stream>>>(scoref, qs_hi, qs_lo, part1,
      2048, 2, 2048, 1024, 2097152L, 131072L, 2097152L, 64L, 16, 128);
  reduce64<<<512, blk, 0, stream>>>(part1, gqs_hi, gqs_lo, 131072, 2);

  // 7) g_scores[bh] = gqs@kk^T * scale, mask -> fp32; softmax in place -> g_attn
  gemm_sp<64,1,1,0,1><<<dim3(16,1,128), blk, 0, stream>>>(
      gqs_hi, gqs_lo, kk_hi, scoref, nullptr, mask_ws,
      64, 64,1024,2048, 65536L,4096L, 2097152L,64L, 2097152L,131072L, 16, 2048, scale);
  softmax_inplace<<<8192, blk, 0, stream>>>(scoref, 2048);

  // 8) gk/gv[bh] = g_attn[bh](64xS) @ {kk,vs}[bh](Sx64) -> fused dual -> planes
  einsum64_dual<<<dim3(2,128), blk, 0, stream>>>(scoref, kk_hi, kk_lo, vs_hi, vs_lo,
      part1, part2, 2048, 2, 2048, 1024, 2097152L, 131072L, 2097152L, 64L, 16, 128);
  reduce64<<<512, blk, 0, stream>>>(part1, gk_hi, gk_lo, 131072, 2);
  reduce64<<<512, blk, 0, stream>>>(part2, gv_hi, gv_lo, 131072, 2);

  // 9) stage 2 (MFMA): l_attn (out1) + attn planes (overlay dead kk planes)
  stage2_mfma<<<dim3(16,128), blk, 0, stream>>>(qs_hi, qs_lo, gk_hi, gk_lo,
      gv_hi, gv_lo, out1, attn_hi, attn_lo, scale);

  // 10) out0 = attn @ Wo (A = attn planes, B = WoT hi plane)
  gemm_sp<128,1,1,0,0><<<dim3(8,128,1), blk, 0, stream>>>(
      attn_hi, attn_lo, WoT_hi, out0, nullptr, nullptr,
      1024, 1024,1024,1024, 0,0, 0,0, 0,0, 1, 2048, 1.f);

  (void)in_sizes; (void)n_in; (void)out_size; (void)ws_size;
}